// Round 9
// baseline (6662.286 us; speedup 1.0000x reference)
//
#include <hip/hip_runtime.h>
#include <stdint.h>

#define HIST 1792
#define TGT 256
#define SEQ 2048
#define INPUT 352
#define EHID 250
#define HID 500

typedef _Float16 h2_t __attribute__((ext_vector_type(2)));

static __device__ __forceinline__ float fdot2(uint32_t a, uint32_t b, float c) {
  return __builtin_amdgcn_fdot2(__builtin_bit_cast(h2_t, a),
                                __builtin_bit_cast(h2_t, b), c, false);
}
static __device__ __forceinline__ uint32_t packh2(float lo, float hi) {
  h2_t h; h[0] = (_Float16)lo; h[1] = (_Float16)hi;
  return __builtin_bit_cast(uint32_t, h);
}
static __device__ __forceinline__ uint4 packq(const float* p) {
  uint4 r;
  r.x = packh2(p[0], p[1]); r.y = packh2(p[2], p[3]);
  r.z = packh2(p[4], p[5]); r.w = packh2(p[6], p[7]);
  return r;
}
static __device__ __forceinline__ float dotq(uint4 w, uint4 h, float acc) {
  acc = fdot2(w.x, h.x, acc); acc = fdot2(w.y, h.y, acc);
  acc = fdot2(w.z, h.z, acc); acc = fdot2(w.w, h.w, acc);
  return acc;
}
static __device__ __forceinline__ float sigf(float x) {
  x = fminf(fmaxf(x, -30.f), 30.f);
  return 1.f / (1.f + __expf(-x));
}
static __device__ __forceinline__ float tanh_f(float x) {
  x = fminf(fmaxf(x, -15.f), 15.f);
  float e = __expf(2.f * x);
  return (e - 1.f) / (e + 1.f);
}
static __device__ __forceinline__ void spin_flag(volatile int* f) {
  while (__hip_atomic_load(f, __ATOMIC_ACQUIRE, __HIP_MEMORY_SCOPE_AGENT) == 0)
    __builtin_amdgcn_s_sleep(2);
}
// AGPR store/load (gfx950 unified file), non-volatile (dataflow-ordered)
#define AW(dst, src) asm("v_accvgpr_write_b32 %0, %1" : "=a"(dst) : "v"(src))
#define AR(dst, src) asm("v_accvgpr_read_b32 %0, %1" : "=v"(dst) : "a"(src))
#define ARQ(dst, arr, base) do { AR(dst.x, arr[(base)+0]); AR(dst.y, arr[(base)+1]); AR(dst.z, arr[(base)+2]); AR(dst.w, arr[(base)+3]); } while(0)

// ---------------- embedding gather + target_emb ----------------
__global__ void k_embed(const int* __restrict__ loc, const int* __restrict__ tim,
                        const int* __restrict__ cid, const int* __restrict__ target,
                        const float* __restrict__ weight, const float* __restrict__ emb_tim_w,
                        const float* __restrict__ weight_cid,
                        float* __restrict__ x, float* __restrict__ te) {
  int t = blockIdx.x, tid = threadIdx.x;
  if (t < SEQ) {
    int l = loc[t], tm = tim[t], cd = cid[t];
    float* xr = x + (size_t)t * INPUT;
    for (int k = tid; k < 256; k += blockDim.x) xr[k] = weight[(size_t)l * 256 + k];
    for (int k = tid; k < 32; k += blockDim.x)  xr[256 + k] = emb_tim_w[tm * 32 + k];
    for (int k = tid; k < 64; k += blockDim.x)  xr[288 + k] = weight_cid[cd * 64 + k];
  } else {
    int i = t - SEQ;
    int tg = target[i];
    for (int k = tid; k < 256; k += blockDim.x) te[(size_t)i * 256 + k] = weight[(size_t)tg * 256 + k];
  }
}

// ---------------- C[M][N] = op(A)[M][K] @ W[N][K]^T + bias ----------------
__global__ void k_gemm_t(const float* __restrict__ A, int lda,
                         const float* __restrict__ W, const float* __restrict__ bias,
                         float* __restrict__ C, int ldc,
                         int M, int N, int K, int revA) {
  __shared__ float As[16][65];
  __shared__ float Ws[16][65];
  const int bn = blockIdx.x * 64, bm = blockIdx.y * 64;
  const int tid = threadIdx.x;
  const int tx = tid & 15, ty = tid >> 4;
  float acc[4][4] = {};
  for (int k0 = 0; k0 < K; k0 += 16) {
    for (int i = tid; i < 1024; i += 256) {
      int m = i >> 4, k = i & 15;
      int gm = bm + m, gk = k0 + k;
      float v = 0.f;
      if (gm < M && gk < K) { int am = revA ? (M - 1 - gm) : gm; v = A[(size_t)am * lda + gk]; }
      As[k][m] = v;
    }
    for (int i = tid; i < 1024; i += 256) {
      int n = i >> 4, k = i & 15;
      int gn = bn + n, gk = k0 + k;
      float v = 0.f;
      if (gn < N && gk < K) v = W[(size_t)gn * K + gk];
      Ws[k][n] = v;
    }
    __syncthreads();
#pragma unroll
    for (int k = 0; k < 16; k++) {
      float a0 = As[k][ty * 4 + 0], a1 = As[k][ty * 4 + 1], a2 = As[k][ty * 4 + 2], a3 = As[k][ty * 4 + 3];
      float b0 = Ws[k][tx * 4 + 0], b1 = Ws[k][tx * 4 + 1], b2 = Ws[k][tx * 4 + 2], b3 = Ws[k][tx * 4 + 3];
      acc[0][0] += a0 * b0; acc[0][1] += a0 * b1; acc[0][2] += a0 * b2; acc[0][3] += a0 * b3;
      acc[1][0] += a1 * b0; acc[1][1] += a1 * b1; acc[1][2] += a1 * b2; acc[1][3] += a1 * b3;
      acc[2][0] += a2 * b0; acc[2][1] += a2 * b1; acc[2][2] += a2 * b2; acc[2][3] += a2 * b3;
      acc[3][0] += a3 * b0; acc[3][1] += a3 * b1; acc[3][2] += a3 * b2; acc[3][3] += a3 * b3;
    }
    __syncthreads();
  }
  for (int i = 0; i < 4; i++) {
    int gm = bm + ty * 4 + i; if (gm >= M) continue;
    for (int j = 0; j < 4; j++) {
      int gn = bn + tx * 4 + j; if (gn >= N) continue;
      C[(size_t)gm * ldc + gn] = acc[i][j] + (bias ? bias[gn] : 0.f);
    }
  }
}

// ---------------- C[M][N] = A[M][K] @ B[K][N] + addvec[N] ----------------
__global__ void k_gemm_nn(const float* __restrict__ A, int lda,
                          const float* __restrict__ B, int ldb,
                          const float* __restrict__ addvec,
                          float* __restrict__ C, int ldc,
                          int M, int N, int K) {
  __shared__ float As[16][65];
  __shared__ float Bs[16][65];
  const int bn = blockIdx.x * 64, bm = blockIdx.y * 64;
  const int tid = threadIdx.x;
  const int tx = tid & 15, ty = tid >> 4;
  float acc[4][4] = {};
  for (int k0 = 0; k0 < K; k0 += 16) {
    for (int i = tid; i < 1024; i += 256) {
      int m = i >> 4, k = i & 15;
      int gm = bm + m, gk = k0 + k;
      float v = 0.f;
      if (gm < M && gk < K) v = A[(size_t)gm * lda + gk];
      As[k][m] = v;
    }
    for (int i = tid; i < 1024; i += 256) {
      int k = i >> 6, n = i & 63;
      int gk = k0 + k, gn = bn + n;
      float v = 0.f;
      if (gk < K && gn < N) v = B[(size_t)gk * ldb + gn];
      Bs[k][n] = v;
    }
    __syncthreads();
#pragma unroll
    for (int k = 0; k < 16; k++) {
      float a0 = As[k][ty * 4 + 0], a1 = As[k][ty * 4 + 1], a2 = As[k][ty * 4 + 2], a3 = As[k][ty * 4 + 3];
      float b0 = Bs[k][tx * 4 + 0], b1 = Bs[k][tx * 4 + 1], b2 = Bs[k][tx * 4 + 2], b3 = Bs[k][tx * 4 + 3];
      acc[0][0] += a0 * b0; acc[0][1] += a0 * b1; acc[0][2] += a0 * b2; acc[0][3] += a0 * b3;
      acc[1][0] += a1 * b0; acc[1][1] += a1 * b1; acc[1][2] += a1 * b2; acc[1][3] += a1 * b3;
      acc[2][0] += a2 * b0; acc[2][1] += a2 * b1; acc[2][2] += a2 * b2; acc[2][3] += a2 * b3;
      acc[3][0] += a3 * b0; acc[3][1] += a3 * b1; acc[3][2] += a3 * b2; acc[3][3] += a3 * b3;
    }
    __syncthreads();
  }
  for (int i = 0; i < 4; i++) {
    int gm = bm + ty * 4 + i; if (gm >= M) continue;
    for (int j = 0; j < 4; j++) {
      int gn = bn + tx * 4 + j; if (gn >= N) continue;
      C[(size_t)gm * ldc + gn] = acc[i][j] + (addvec ? addvec[gn] : 0.f);
    }
  }
}

// ---------------- LSTMs (K-quartered) ----------------
// 6 blocks x 512 threads. lane = 16*kq + r (kq = K-quarter, r = slot-in-wave).
// slot = wave*16 + r in [0,128).
//  b0,b1 encoders: slot owns cells {2s,2s+1} x 4 gates (8 rows); lane holds
//    the kq-quarter (64 f16) of each row: 64 quads = 20 VGPR + 32 AGPR + 12 LDS.
//    z is lane-local after shfl-reduce (xor 16,32); 1 barrier/step.
//  b2..b5 decoder gate-blocks: slot owns 4 cells of gate g; quarter = 128 f16.
//    One cross-block RT/step: publish z(float4), spin 3 flags, replicate c/h.
// h stored kq-interleaved in LDS: quad(q,kq) = q*4+kq -> the 4 quarter-groups
// hit disjoint bank sets (conflict-free); h-reads/wave: 8 (enc) / 16 (dec).
#define WQL 12
__launch_bounds__(512)
__global__ void k_lstm(const float* __restrict__ A_f, const float* __restrict__ A_b,
                       const float* __restrict__ A_d,
                       const float* __restrict__ Whh_f, const float* __restrict__ Whh_b,
                       const float* __restrict__ Whh_d,
                       float* __restrict__ hh, float* __restrict__ hdec,
                       float* zpub, int* flag_z) {
  const int b = blockIdx.x;
  const int tid = threadIdx.x;
  __shared__ __align__(16) uint4 wl[WQL * 512];   // 98,304 B weight tails
  __shared__ __align__(16) uint4 h4[128];         // 2 KiB: 2 buffers (enc 32q, dec 64q)
  const int lane = tid & 63;
  const int wid = tid >> 6;
  const int r = lane & 15;
  const int kq = lane >> 4;
  const int slot = wid * 16 + r;                  // 0..127

  if (tid < 128) h4[tid] = make_uint4(0, 0, 0, 0);

  if (b < 2) {
    // ================= encoder =================
    const float* A = b ? A_b : A_f;
    const float* Whh = b ? Whh_b : Whh_f;
    const int c0 = slot * 2;
    const bool vcell = c0 < EHID;                 // c0 even; c0<250 => c0+1<=249
    uint4 wv[20];
    uint32_t wa[128];
    // weights: row ri = g*2+j -> row g*250+c0+j, quarter cols kq*64+q*8..+8
#pragma unroll
    for (int g = 0; g < 4; g++)
#pragma unroll
      for (int j = 0; j < 2; j++) {
        const int ri = g * 2 + j;
        const int rowc = g * 250 + (vcell ? (c0 + j) : 249);  // clamped, values masked
        const float* wr = Whh + (size_t)rowc * EHID;
#pragma unroll
        for (int q = 0; q < 8; q++) {
          float tmp[8];
#pragma unroll
          for (int cc = 0; cc < 8; cc++) {
            int col = kq * 64 + q * 8 + cc;
            tmp[cc] = (vcell && col < EHID) ? wr[col] : 0.f;
          }
          uint4 pq = packq(tmp);
          const int wq = ri * 8 + q;
          if (wq < 20) wv[wq] = pq;
          else if (wq < 52) {
            AW(wa[(wq - 20) * 4 + 0], pq.x); AW(wa[(wq - 20) * 4 + 1], pq.y);
            AW(wa[(wq - 20) * 4 + 2], pq.z); AW(wa[(wq - 20) * 4 + 3], pq.w);
          } else wl[(wq - 52) * 512 + tid] = pq;
        }
      }
    float cs0 = 0.f, cs1 = 0.f;
    float aN[8];
    if (kq == 0 && vcell) {
#pragma unroll
      for (int g = 0; g < 4; g++) {
        float2 v = *(const float2*)(A + (size_t)g * 250 + c0);
        aN[g * 2] = v.x; aN[g * 2 + 1] = v.y;
      }
    }
    __syncthreads();
    for (int t = 0; t < HIST; t++) {
      const uint4* hb = h4 + (t & 1) * 32;
      float aC[8];
#pragma unroll
      for (int i = 0; i < 8; i++) aC[i] = aN[i];
      if (kq == 0 && vcell) {
        int tn = (t + 1 < HIST) ? t + 1 : t;
#pragma unroll
        for (int g = 0; g < 4; g++) {
          float2 v = *(const float2*)(A + (size_t)tn * 1000 + g * 250 + c0);
          aN[g * 2] = v.x; aN[g * 2 + 1] = v.y;
        }
      }
      float p[8] = {0.f, 0.f, 0.f, 0.f, 0.f, 0.f, 0.f, 0.f};
#pragma unroll
      for (int q = 0; q < 8; q++) {
        const uint4 hq = hb[q * 4 + kq];
#pragma unroll
        for (int ri = 0; ri < 8; ri++) {
          const int wq = ri * 8 + q;
          uint4 u;
          if (wq < 20) u = wv[wq];
          else if (wq < 52) { ARQ(u, wa, (wq - 20) * 4); }
          else u = wl[(wq - 52) * 512 + tid];
          p[ri] = dotq(u, hq, p[ri]);
        }
      }
#pragma unroll
      for (int ri = 0; ri < 8; ri++) {
        p[ri] += __shfl_xor(p[ri], 16);
        p[ri] += __shfl_xor(p[ri], 32);
      }
      if (kq == 0 && vcell) {
        float zi0 = p[0] + aC[0], zi1 = p[1] + aC[1];
        float zf0 = p[2] + aC[2], zf1 = p[3] + aC[3];
        float zg0 = p[4] + aC[4], zg1 = p[5] + aC[5];
        float zo0 = p[6] + aC[6], zo1 = p[7] + aC[7];
        cs0 = sigf(zf0) * cs0 + sigf(zi0) * tanh_f(zg0);
        float h0 = sigf(zo0) * tanh_f(cs0);
        cs1 = sigf(zf1) * cs1 + sigf(zi1) * tanh_f(zg1);
        float h1 = sigf(zo1) * tanh_f(cs1);
        if (b == 0) *(float2*)(hh + (size_t)t * HID + c0) = make_float2(h0, h1);
        else        *(float2*)(hh + (size_t)(HIST - 1 - t) * HID + EHID + c0) = make_float2(h0, h1);
        // kq-interleaved h write: cells {2s,2s+1} -> phys dword
        const int s = slot;
        const int physd = (((s & 31) >> 2) * 4 + (s >> 5)) * 4 + (s & 3);
        ((uint32_t*)(h4 + ((t + 1) & 1) * 32))[physd] = packh2(h0, h1);
      }
      __syncthreads();
    }
  } else {
    // ================= decoder =================
    const int g = b - 2;
    const int c0 = slot * 4;
    const bool vcell = c0 < HID;
    uint4 wv[20];
    uint32_t wa[128];
    // rows j=0..3 -> g*500+c0+j; quarter cols kq*128 + q*8..+8, q=0..15
#pragma unroll
    for (int j = 0; j < 4; j++) {
      const int rowc = g * 500 + (vcell ? (c0 + j) : 499);
      const float* wr = Whh_d + (size_t)rowc * HID;
#pragma unroll
      for (int q = 0; q < 16; q++) {
        float tmp[8];
#pragma unroll
        for (int cc = 0; cc < 8; cc++) {
          int col = kq * 128 + q * 8 + cc;
          tmp[cc] = (vcell && col < HID) ? wr[col] : 0.f;
        }
        uint4 pq = packq(tmp);
        const int wq = j * 16 + q;
        if (wq < 20) wv[wq] = pq;
        else if (wq < 52) {
          AW(wa[(wq - 20) * 4 + 0], pq.x); AW(wa[(wq - 20) * 4 + 1], pq.y);
          AW(wa[(wq - 20) * 4 + 2], pq.z); AW(wa[(wq - 20) * 4 + 3], pq.w);
        } else wl[(wq - 52) * 512 + tid] = pq;
      }
    }
    float cs0 = 0.f, cs1 = 0.f, cs2 = 0.f, cs3 = 0.f;
    float4 aN = make_float4(0.f, 0.f, 0.f, 0.f);
    if (kq == 0 && vcell) aN = *(const float4*)(A_d + (size_t)g * 500 + c0);
    __syncthreads();
    for (int t = 0; t < TGT; t++) {
      const uint4* hb = h4 + (t & 1) * 64;
      float4 aC = aN;
      if (kq == 0 && vcell) {
        int tn = (t + 1 < TGT) ? t + 1 : t;
        aN = *(const float4*)(A_d + (size_t)tn * 2000 + g * 500 + c0);
      }
      float p[4] = {0.f, 0.f, 0.f, 0.f};
#pragma unroll
      for (int q = 0; q < 16; q++) {
        const uint4 hq = hb[q * 4 + kq];
#pragma unroll
        for (int j = 0; j < 4; j++) {
          const int wq = j * 16 + q;
          uint4 u;
          if (wq < 20) u = wv[wq];
          else if (wq < 52) { ARQ(u, wa, (wq - 20) * 4); }
          else u = wl[(wq - 52) * 512 + tid];
          p[j] = dotq(u, hq, p[j]);
        }
      }
#pragma unroll
      for (int j = 0; j < 4; j++) {
        p[j] += __shfl_xor(p[j], 16);
        p[j] += __shfl_xor(p[j], 32);
      }
      float* zp = zpub + (t & 1) * 2048;
      if (kq == 0 && vcell)
        *(float4*)(zp + g * 512 + c0) =
            make_float4(p[0] + aC.x, p[1] + aC.y, p[2] + aC.z, p[3] + aC.w);
      __threadfence();
      __syncthreads();
      if (tid == 0) {
        __hip_atomic_store(&flag_z[t * 4 + g], 1, __ATOMIC_RELEASE, __HIP_MEMORY_SCOPE_AGENT);
        for (int gg = 0; gg < 4; gg++)
          if (gg != g) spin_flag(&flag_z[t * 4 + gg]);
      }
      __syncthreads();
      if (kq == 0 && vcell) {
        float zz[4][4];
#pragma unroll
        for (int gg = 0; gg < 4; gg++)
#pragma unroll
          for (int j = 0; j < 4; j++)
            zz[gg][j] = __hip_atomic_load(&zp[gg * 512 + c0 + j], __ATOMIC_RELAXED, __HIP_MEMORY_SCOPE_AGENT);
        cs0 = sigf(zz[1][0]) * cs0 + sigf(zz[0][0]) * tanh_f(zz[2][0]);
        float h0 = sigf(zz[3][0]) * tanh_f(cs0);
        cs1 = sigf(zz[1][1]) * cs1 + sigf(zz[0][1]) * tanh_f(zz[2][1]);
        float h1 = sigf(zz[3][1]) * tanh_f(cs1);
        cs2 = sigf(zz[1][2]) * cs2 + sigf(zz[0][2]) * tanh_f(zz[2][2]);
        float h2 = sigf(zz[3][2]) * tanh_f(cs2);
        cs3 = sigf(zz[1][3]) * cs3 + sigf(zz[0][3]) * tanh_f(zz[2][3]);
        float h3 = sigf(zz[3][3]) * tanh_f(cs3);
        if (g == 3) *(float4*)(hdec + (size_t)t * HID + c0) = make_float4(h0, h1, h2, h3);
        // kq-interleaved h write: cells {4s..4s+3} -> phys dwords (b64)
        const int s = slot;
        const int physd = (((s & 31) >> 1) * 4 + (s >> 5)) * 4 + (s & 1) * 2;
        ((uint2*)(h4 + ((t + 1) & 1) * 64))[physd >> 1] =
            make_uint2(packh2(h0, h1), packh2(h2, h3));
      }
      __syncthreads();
    }
  }
}

// ---------------- attention tables: S1 (256x1792), S2 (256x256) ----------------
__global__ void k_attn(const int* __restrict__ loc, const int* __restrict__ tim,
                       const int* __restrict__ cid,
                       const float* __restrict__ ts, const float* __restrict__ pd,
                       const float* __restrict__ pct,
                       float* __restrict__ S1, float* __restrict__ S2) {
  const int i = blockIdx.x;
  const int tid = threadIdx.x; // 256
  __shared__ float e[HIST];
  __shared__ float red[256];
  const int loc_i = loc[HIST + i], tim_i = tim[HIST + i];
  for (int tab = 0; tab < 3; tab++) {
    for (int jj = tid; jj < HIST; jj += 256) {
      float v;
      if (tab == 0)      v = 1.f / pd[(size_t)loc_i * 10000 + loc[jj]];
      else if (tab == 1) v = ts[tim_i * 48 + tim[jj]];
      else               v = pct[tim_i * 300 + cid[jj]];
      e[jj] = v;
    }
    __syncthreads();
    float mx = -1e30f;
    for (int jj = tid; jj < HIST; jj += 256) mx = fmaxf(mx, e[jj]);
    red[tid] = mx; __syncthreads();
    for (int s = 128; s > 0; s >>= 1) { if (tid < s) red[tid] = fmaxf(red[tid], red[tid + s]); __syncthreads(); }
    mx = red[0]; __syncthreads();
    float sm = 0.f;
    for (int jj = tid; jj < HIST; jj += 256) sm += __expf(e[jj] - mx);
    red[tid] = sm; __syncthreads();
    for (int s = 128; s > 0; s >>= 1) { if (tid < s) red[tid] += red[tid + s]; __syncthreads(); }
    float inv = 1.f / red[0]; __syncthreads();
    for (int jj = tid; jj < HIST; jj += 256) {
      float p = __expf(e[jj] - mx) * inv;
      if (tab == 0) S1[(size_t)i * HIST + jj] = p; else S1[(size_t)i * HIST + jj] += p;
    }
    __syncthreads();
  }
  const int lj = loc[HIST + tid], tj = tim[HIST + tid], cj = cid[HIST + tid];
  for (int tab = 0; tab < 3; tab++) {
    float v;
    if (tab == 0)      v = 1.f / pd[(size_t)loc_i * 10000 + lj];
    else if (tab == 1) v = ts[tim_i * 48 + tj];
    else               v = pct[tim_i * 300 + cj];
    if (tid > i) v = 0.f;
    red[tid] = v; __syncthreads();
    for (int s = 128; s > 0; s >>= 1) { if (tid < s) red[tid] = fmaxf(red[tid], red[tid + s]); __syncthreads(); }
    float mx = red[0]; __syncthreads();
    float ex = __expf(v - mx);
    red[tid] = ex; __syncthreads();
    for (int s = 128; s > 0; s >>= 1) { if (tid < s) red[tid] += red[tid + s]; __syncthreads(); }
    float p = ex / red[0]; __syncthreads();
    if (tab == 0) S2[(size_t)i * TGT + tid] = p; else S2[(size_t)i * TGT + tid] += p;
    __syncthreads();
  }
}

// ---------------- uid_emb ----------------
__global__ void k_uid(const int* __restrict__ uid, const float* __restrict__ emb_uid_w,
                      const float* __restrict__ fc_user_w, const float* __restrict__ fc_user_b,
                      float* __restrict__ uid_emb) {
  const int tid = threadIdx.x; // 512
  __shared__ float u[64];
  if (tid < 64) u[tid] = emb_uid_w[(size_t)uid[0] * 64 + tid];
  __syncthreads();
  if (tid < HID) {
    float a = fc_user_b[tid];
    for (int k = 0; k < 64; k++) a += u[k] * fc_user_w[tid * 64 + k];
    uid_emb[tid] = a;
  }
}

// ---------------- user attention + context_user ----------------
__global__ void k_user(const float* __restrict__ uid_emb, const float* __restrict__ hh,
                       float* __restrict__ out) {
  const int tid = threadIdx.x; // 1024
  __shared__ float s[HIST];
  __shared__ float red[1024];
  __shared__ float ue[HID];
  if (tid < HID) ue[tid] = uid_emb[tid];
  __syncthreads();
  for (int t = tid; t < HIST; t += 1024) {
    float a = 0.f;
    const float* hr = hh + (size_t)t * HID;
    for (int k = 0; k < HID; k++) a += ue[k] * hr[k];
    s[t] = a;
  }
  __syncthreads();
  float mx = -1e30f;
  for (int t = tid; t < HIST; t += 1024) mx = fmaxf(mx, s[t]);
  red[tid] = mx; __syncthreads();
  for (int st = 512; st > 0; st >>= 1) { if (tid < st) red[tid] = fmaxf(red[tid], red[tid + st]); __syncthreads(); }
  mx = red[0]; __syncthreads();
  float sm = 0.f;
  for (int t = tid; t < HIST; t += 1024) sm += __expf(s[t] - mx);
  red[tid] = sm; __syncthreads();
  for (int st = 512; st > 0; st >>= 1) { if (tid < st) red[tid] += red[tid + st]; __syncthreads(); }
  float inv = 1.f / red[0]; __syncthreads();
  for (int t = tid; t < HIST; t += 1024) s[t] = __expf(s[t] - mx) * inv;
  __syncthreads();
  if (tid < HID) {
    float a = 0.f;
    for (int t = 0; t < HIST; t++) a += s[t] * hh[(size_t)t * HID + tid];
    for (int i = 0; i < TGT; i++) out[(size_t)i * 1500 + 1000 + tid] = a;
  }
}

// ---------------- in-place log-softmax ----------------
__global__ void k_logsoftmax(float* __restrict__ y) {
  const int i = blockIdx.x;
  const int tid = threadIdx.x; // 1024
  float* r = y + (size_t)i * 10000;
  __shared__ float red[1024];
  float mx = -1e30f;
  for (int j = tid; j < 10000; j += 1024) mx = fmaxf(mx, r[j]);
  red[tid] = mx; __syncthreads();
  for (int s = 512; s > 0; s >>= 1) { if (tid < s) red[tid] = fmaxf(red[tid], red[tid + s]); __syncthreads(); }
  mx = red[0]; __syncthreads();
  float sm = 0.f;
  for (int j = tid; j < 10000; j += 1024) sm += __expf(r[j] - mx);
  red[tid] = sm; __syncthreads();
  for (int s = 512; s > 0; s >>= 1) { if (tid < s) red[tid] += red[tid + s]; __syncthreads(); }
  float lse = mx + __logf(red[0]);
  __syncthreads();
  for (int j = tid; j < 10000; j += 1024) r[j] = r[j] - lse;
}

extern "C" void kernel_launch(void* const* d_in, const int* in_sizes, int n_in,
                              void* d_out, int out_size, void* d_ws, size_t ws_size,
                              hipStream_t stream) {
  (void)in_sizes; (void)n_in; (void)out_size; (void)ws_size;
  const int* loc = (const int*)d_in[0];
  const int* tim = (const int*)d_in[1];
  const int* cid = (const int*)d_in[2];
  const int* uid = (const int*)d_in[3];
  const int* target = (const int*)d_in[4];
  const float* ts = (const float*)d_in[6];
  const float* pd = (const float*)d_in[7];
  const float* pct = (const float*)d_in[8];
  const float* weight = (const float*)d_in[9];
  const float* weight_cid = (const float*)d_in[10];
  const float* emb_uid_w = (const float*)d_in[11];
  const float* emb_tim_w = (const float*)d_in[12];
  const float* enc_Wih_f = (const float*)d_in[13];
  const float* enc_Whh_f = (const float*)d_in[14];
  const float* enc_b_f = (const float*)d_in[15];
  const float* enc_Wih_b = (const float*)d_in[16];
  const float* enc_Whh_b = (const float*)d_in[17];
  const float* enc_b_b = (const float*)d_in[18];
  const float* dec_Wih = (const float*)d_in[19];
  const float* dec_Whh = (const float*)d_in[20];
  const float* dec_b = (const float*)d_in[21];
  const float* fc_user_w = (const float*)d_in[22];
  const float* fc_user_b = (const float*)d_in[23];
  const float* fc_final_w = (const float*)d_in[24];
  const float* fc_final_b = (const float*)d_in[25];
  const float* fc_final2_w = (const float*)d_in[26];
  const float* fc_final2_b = (const float*)d_in[27];

  float* score = (float*)d_out;                  // 256*10000
  float* y1 = score + (size_t)TGT * 10000;       // 256*500
  float* te = y1 + (size_t)TGT * HID;            // 256*256

  float* ws = (float*)d_ws;
  float* x = ws;                                  // SEQ*INPUT
  float* A_f = x + (size_t)SEQ * INPUT;           // HIST*1000
  float* A_b = A_f + (size_t)HIST * 1000;         // HIST*1000
  float* A_d = A_b + (size_t)HIST * 1000;         // TGT*2000
  float* hh = A_d + (size_t)TGT * 2000;           // HIST*500
  float* hdec = hh + (size_t)HIST * HID;          // TGT*500
  float* S1 = hdec + (size_t)TGT * HID;           // TGT*HIST
  float* S2 = S1 + (size_t)TGT * HIST;            // TGT*TGT
  float* outb = S2 + (size_t)TGT * TGT;           // TGT*1500
  float* uid_emb = outb + (size_t)TGT * 1500;     // 512
  float* zpub = uid_emb + 512;                    // 2 * 4 * 512
  int* flag_z = (int*)(zpub + 2 * 2048);          // 4*TGT

  k_embed<<<dim3(SEQ + TGT), dim3(128), 0, stream>>>(loc, tim, cid, target, weight, emb_tim_w, weight_cid, x, te);

  k_gemm_t<<<dim3(16, 28), dim3(256), 0, stream>>>(x, INPUT, enc_Wih_f, enc_b_f, A_f, 1000, HIST, 1000, INPUT, 0);
  k_gemm_t<<<dim3(16, 28), dim3(256), 0, stream>>>(x, INPUT, enc_Wih_b, enc_b_b, A_b, 1000, HIST, 1000, INPUT, 1);
  k_gemm_t<<<dim3(32, 4), dim3(256), 0, stream>>>(x + (size_t)HIST * INPUT, INPUT, dec_Wih, dec_b, A_d, 2000, TGT, 2000, INPUT, 0);

  hipMemsetAsync(flag_z, 0, 4 * TGT * sizeof(int), stream);

  k_attn<<<dim3(TGT), dim3(256), 0, stream>>>(loc, tim, cid, ts, pd, pct, S1, S2);
  k_uid<<<dim3(1), dim3(512), 0, stream>>>(uid, emb_uid_w, fc_user_w, fc_user_b, uid_emb);

  k_lstm<<<dim3(6), dim3(512), 0, stream>>>(A_f, A_b, A_d, enc_Whh_f, enc_Whh_b, dec_Whh,
                                            hh, hdec, zpub, flag_z);

  k_user<<<dim3(1), dim3(1024), 0, stream>>>(uid_emb, hh, outb);
  k_gemm_nn<<<dim3(8, 4), dim3(256), 0, stream>>>(S2, TGT, hdec, HID, uid_emb, outb, 1500, TGT, HID, TGT);
  k_gemm_nn<<<dim3(8, 4), dim3(256), 0, stream>>>(S1, HIST, hh, HID, nullptr, outb + 500, 1500, TGT, HID, HIST);

  k_gemm_t<<<dim3(157, 4), dim3(256), 0, stream>>>(outb, 1500, fc_final_w, fc_final_b, score, 10000, TGT, 10000, 1500, 0);
  k_gemm_t<<<dim3(8, 4), dim3(256), 0, stream>>>(outb, 1500, fc_final2_w, fc_final2_b, y1, 500, TGT, 500, 1500, 0);

  k_logsoftmax<<<dim3(TGT), dim3(1024), 0, stream>>>(score);
}